// Round 4
// baseline (221.958 us; speedup 1.0000x reference)
//
#include <hip/hip_runtime.h>
#include <math.h>

// Problem constants
#define GNUM 64
#define DDIM 64
#define EDIM 32
#define UNK_CLASS 80
#define DBLK 512                  // density blocks: one thread per pixel (8*16384/256)
#define ABLK 4096                 // AE blocks: 32KB contiguous per block
#define NBLK (DBLK + ABLK)

// Split-range grid, one kernel:
//   b <  DBLK : density MLP + anchor matching. ALL weights/boxes are wave-uniform
//               -> read from global with uniform indices so the compiler emits
//               s_load into SGPRs (scalar K$). ZERO LDS data traffic: rounds 1-3
//               were dominated (~60us) by ~576 broadcast ds_read_b128 per thread
//               serializing on the per-CU LDS pipe (SQ_LDS_BANK_CONFLICT=591).
//   b >= DBLK : pure AE streaming, 8 float4 per thread, block-contiguous 32KB.
// Density blocks start instantly and finish ~10us, hidden under the ~21us
// BW-bound AE stream.
__global__ __launch_bounds__(256) void fused_kernel(
    const float* __restrict__ err,        // [N,256,128,128]
    const float* __restrict__ err_map,    // [N,1,128,128]
    const float* __restrict__ gt_boxes,   // [N,64,4]
    const float* __restrict__ w1,         // [1,64]
    const float* __restrict__ b1,         // [64]
    const float* __restrict__ w2,         // [64,32] row-major
    const float* __restrict__ b2,         // [32]
    const float* __restrict__ w3,         // [32,1]
    const float* __restrict__ b3,         // [1]
    const int*   __restrict__ gt_classes, // [N,64]
    float* __restrict__ ws)               // [NBLK] per-block partials
{
    const int t = threadIdx.x;
    const int b = blockIdx.x;
    float part = 0.0f;
    __shared__ float red[4];

    if (b >= DBLK) {
        // ---------------- AE sum-of-squares: 8 loads in flight, 32KB/block ----
        const float4* __restrict__ e4 = (const float4*)err;
        const int base = (b - DBLK) * 2048 + t;           // block-contiguous chunk
        float4 v0 = e4[base + 0*256];
        float4 v1 = e4[base + 1*256];
        float4 v2 = e4[base + 2*256];
        float4 v3 = e4[base + 3*256];
        float4 v4 = e4[base + 4*256];
        float4 v5 = e4[base + 5*256];
        float4 v6 = e4[base + 6*256];
        float4 v7 = e4[base + 7*256];
        float s0, s1, s2, s3;
        s0 = v0.x*v0.x; s1 = v0.y*v0.y; s2 = v0.z*v0.z; s3 = v0.w*v0.w;
        s0 = fmaf(v1.x,v1.x,s0); s1 = fmaf(v1.y,v1.y,s1); s2 = fmaf(v1.z,v1.z,s2); s3 = fmaf(v1.w,v1.w,s3);
        s0 = fmaf(v2.x,v2.x,s0); s1 = fmaf(v2.y,v2.y,s1); s2 = fmaf(v2.z,v2.z,s2); s3 = fmaf(v2.w,v2.w,s3);
        s0 = fmaf(v3.x,v3.x,s0); s1 = fmaf(v3.y,v3.y,s1); s2 = fmaf(v3.z,v3.z,s2); s3 = fmaf(v3.w,v3.w,s3);
        s0 = fmaf(v4.x,v4.x,s0); s1 = fmaf(v4.y,v4.y,s1); s2 = fmaf(v4.z,v4.z,s2); s3 = fmaf(v4.w,v4.w,s3);
        s0 = fmaf(v5.x,v5.x,s0); s1 = fmaf(v5.y,v5.y,s1); s2 = fmaf(v5.z,v5.z,s2); s3 = fmaf(v5.w,v5.w,s3);
        s0 = fmaf(v6.x,v6.x,s0); s1 = fmaf(v6.y,v6.y,s1); s2 = fmaf(v6.z,v6.z,s2); s3 = fmaf(v6.w,v6.w,s3);
        s0 = fmaf(v7.x,v7.x,s0); s1 = fmaf(v7.y,v7.y,s1); s2 = fmaf(v7.z,v7.z,s2); s3 = fmaf(v7.w,v7.w,s3);
        part = (s0+s1) + (s2+s3);
    } else {
        // ---------------- density + anchor matching (no LDS, SMEM weights) ----
        const int n  = b >> 6;                 // image
        const int m  = ((b & 63) << 8) | t;    // pixel in [0,16384)

        // ---- anchors at this pixel (A=3 aspect ratios, detectron2 order) ----
        const float cx = (float)(m & 127) * 8.0f;
        const float cy = (float)(m >> 7) * 8.0f;
        const float s05 = sqrtf(0.5f), s2r = sqrtf(2.0f);
        const float hw0 = 0.5f*(32.0f/s05), hh0 = 0.5f*(32.0f*s05);
        const float hw1 = 16.0f,            hh1 = 16.0f;
        const float hw2 = 0.5f*(32.0f/s2r), hh2 = 0.5f*(32.0f*s2r);

        const float ax1[3] = {cx-hw0, cx-hw1, cx-hw2};
        const float ay1[3] = {cy-hh0, cy-hh1, cy-hh2};
        const float ax2[3] = {cx+hw0, cx+hw1, cx+hw2};
        const float ay2[3] = {cy+hh0, cy+hh1, cy+hh2};
        float areaA[3];
        #pragma unroll
        for (int a = 0; a < 3; ++a) areaA[a] = (ax2[a]-ax1[a])*(ay2[a]-ay1[a]);

        // per-anchor best GT (division-free argmax: iou = inter/dn, dn > 0)
        float bi[3] = {-1.f,-1.f,-1.f}, bd[3] = {1.f,1.f,1.f};
        int   idx[3] = {0,0,0};

        const float* __restrict__ bp = gt_boxes + n*GNUM*4;   // uniform -> s_load
        #pragma unroll 4
        for (int g = 0; g < GNUM; ++g) {
            const float bx1 = bp[4*g+0], by1 = bp[4*g+1];
            const float bx2 = bp[4*g+2], by2 = bp[4*g+3];
            const float areaB = (bx2-bx1)*(by2-by1);
            #pragma unroll
            for (int a = 0; a < 3; ++a) {
                float lx = fmaxf(bx1, ax1[a]), ly = fmaxf(by1, ay1[a]);
                float rx = fminf(bx2, ax2[a]), ry = fminf(by2, ay2[a]);
                float iw = fmaxf(rx-lx, 0.f),  ih = fmaxf(ry-ly, 0.f);
                float inter = iw*ih;
                float dn = fmaxf(areaB + areaA[a] - inter, 1e-9f);
                // strict > keeps FIRST max, matching jnp.argmax
                if (inter*bd[a] > bi[a]*dn) { bi[a]=inter; bd[a]=dn; idx[a]=g; }
            }
        }
        const int* __restrict__ cp = gt_classes + n*GNUM;
        const bool unk = (cp[idx[0]] == UNK_CLASS) |
                         (cp[idx[1]] == UNK_CLASS) |
                         (cp[idx[2]] == UNK_CLASS);
        const float mask = unk ? 1.0f : 0.0f;

        // ---- density MLP, weights via uniform (scalar) loads ----
        const float xv = err_map[(n << 14) + m];
        float acc[EDIM];
        #pragma unroll
        for (int e = 0; e < EDIM; ++e) acc[e] = b2[e];        // uniform -> s_load

        #pragma unroll 2
        for (int d = 0; d < DDIM; ++d) {
            const float h = fmaxf(fmaf(xv, w1[d], b1[d]), 0.0f);
            const float* __restrict__ wr = w2 + d*EDIM;       // uniform row -> s_load
            #pragma unroll
            for (int e = 0; e < EDIM; ++e)
                acc[e] = fmaf(h, wr[e], acc[e]);              // v_fmac v, s, v
        }
        float p = b3[0];
        #pragma unroll
        for (int e = 0; e < EDIM; ++e)
            p = fmaf(fmaxf(acc[e], 0.0f), w3[e], p);

        // stable BCE-with-logits term: logaddexp(0,p) - p*mask
        part = fmaxf(p, 0.0f) + log1pf(expf(-fabsf(p))) - p*mask;
    }

    // ---- block reduction -> ws[b] (each block contributes one partial) ----
    float x = part;
    #pragma unroll
    for (int off = 32; off > 0; off >>= 1) x += __shfl_xor(x, off, 64);
    if ((t & 63) == 0) red[t >> 6] = x;
    __syncthreads();
    if (t == 0) ws[b] = (red[0]+red[1]) + (red[2]+red[3]);
}

__global__ __launch_bounds__(256) void finalize_kernel(const float* __restrict__ ws,
                                                       float* __restrict__ out)
{
    const int t = threadIdx.x;
    float sd = 0.f, sa = 0.f;
    for (int i = t; i < DBLK; i += 256) sd += ws[i];
    for (int i = DBLK + t; i < NBLK; i += 256) sa += ws[i];
    #pragma unroll
    for (int off = 32; off > 0; off >>= 1) {
        sd += __shfl_xor(sd, off, 64);
        sa += __shfl_xor(sa, off, 64);
    }
    __shared__ float rd[4], ra[4];
    if ((t & 63) == 0) { rd[t >> 6] = sd; ra[t >> 6] = sa; }
    __syncthreads();
    if (t == 0) {
        out[0] = ((ra[0]+ra[1])+(ra[2]+ra[3])) * (1.0f/33554432.0f); // loss_ae
        out[1] = ((rd[0]+rd[1])+(rd[2]+rd[3])) * (1.0f/131072.0f);   // loss_density
    }
}

extern "C" void kernel_launch(void* const* d_in, const int* in_sizes, int n_in,
                              void* d_out, int out_size, void* d_ws, size_t ws_size,
                              hipStream_t stream) {
    const float* err        = (const float*)d_in[0];
    const float* err_map    = (const float*)d_in[1];
    const float* gt_boxes   = (const float*)d_in[2];
    const float* w1         = (const float*)d_in[3];
    const float* b1         = (const float*)d_in[4];
    const float* w2         = (const float*)d_in[5];
    const float* b2         = (const float*)d_in[6];
    const float* w3         = (const float*)d_in[7];
    const float* b3         = (const float*)d_in[8];
    const int*   gt_classes = (const int*)d_in[9];
    float* out = (float*)d_out;
    float* ws  = (float*)d_ws;

    fused_kernel<<<NBLK, 256, 0, stream>>>(err, err_map, gt_boxes, w1, b1, w2, b2,
                                           w3, b3, gt_classes, ws);
    finalize_kernel<<<1, 256, 0, stream>>>(ws, out);
}